// Round 9
// baseline (503.831 us; speedup 1.0000x reference)
//
#include <hip/hip_runtime.h>
#include <hip/hip_bf16.h>
#include <math.h>

typedef unsigned short u16;
typedef unsigned int   u32;

#define CC 512
#define NN 196
#define TT 4
#define BB 32
#define TBB 128
#define NHH 8
#define HD 64

// compact-row layout: row = tb*196 + n, M = 128*196 = 25088 rows
#define MROWS   25088
#define ROWS_T  6272                      // rows per t-slice (32*196)
#define CSTRIDE ((size_t)ROWS_T * CC)     // elems per t-slice = 3,211,264

typedef __attribute__((ext_vector_type(8))) short bf16x8;
typedef __attribute__((ext_vector_type(4))) float f32x4;

__device__ __forceinline__ u16 f2bf(float f) {
    __hip_bfloat16 h = __float2bfloat16(f);
    return *(u16*)&h;
}
__device__ __forceinline__ float bf2f(u16 u) {
    u32 ui = ((u32)u) << 16;
    return __uint_as_float(ui);
}
__device__ __forceinline__ u32 pk2(u16 a, u16 b) { return (u32)a | ((u32)b << 16); }

// async 16B/lane global->LDS; lds base must be wave-uniform
__device__ __forceinline__ void gld16(const void* g, void* l) {
    __builtin_amdgcn_global_load_lds(
        (const __attribute__((address_space(1))) void*)g,
        (__attribute__((address_space(3))) void*)l, 16, 0, 0);
}

// ---------------- merged prep: W 3-split (blocks 0..4095) + BN folds (blocks 4096..4103) ----------------
__global__ __launch_bounds__(256) void k_prep(
    const float* __restrict__ qw, const float* __restrict__ kw,
    const float* __restrict__ vw, const float* __restrict__ pw,
    const float* __restrict__ cb0, const float* __restrict__ bg0, const float* __restrict__ bb0,
    const float* __restrict__ bm0, const float* __restrict__ bv0,
    const float* __restrict__ cb1, const float* __restrict__ bg1, const float* __restrict__ bb1,
    const float* __restrict__ bm1, const float* __restrict__ bv1,
    const float* __restrict__ cb2, const float* __restrict__ bg2, const float* __restrict__ bb2,
    const float* __restrict__ bm2, const float* __restrict__ bv2,
    const float* __restrict__ cb3, const float* __restrict__ bg3, const float* __restrict__ bb3,
    const float* __restrict__ bm3, const float* __restrict__ bv3,
    u16* __restrict__ W3, float* __restrict__ SS, float* __restrict__ SH) {
    if (blockIdx.x < 4096) {
        size_t idx = (size_t)blockIdx.x * 256 + threadIdx.x;   // 4 * 262144
        int g = (int)(idx >> 18);
        size_t rem = idx & 262143;
        const float* Ws = (g == 0) ? qw : (g == 1) ? kw : (g == 2) ? vw : pw;
        float w  = Ws[rem];
        u16 u0 = f2bf(w);      float b0 = bf2f(u0);
        float r1 = w - b0;
        u16 u1 = f2bf(r1);     float b1 = bf2f(u1);
        float r2 = r1 - b1;
        u16 u2 = f2bf(r2);
        size_t base = (size_t)g * 786432 + rem;
        W3[base] = u0; W3[base + 262144] = u1; W3[base + 524288] = u2;
        return;
    }
    int idx = (blockIdx.x - 4096) * 256 + threadIdx.x;   // 0..2047
    int g = idx >> 9, o = idx & 511;
    const float* cb = g == 0 ? cb0 : g == 1 ? cb1 : g == 2 ? cb2 : cb3;
    const float* bg = g == 0 ? bg0 : g == 1 ? bg1 : g == 2 ? bg2 : bg3;
    const float* bb = g == 0 ? bb0 : g == 1 ? bb1 : g == 2 ? bb2 : bb3;
    const float* bm = g == 0 ? bm0 : g == 1 ? bm1 : g == 2 ? bm2 : bm3;
    const float* bv = g == 0 ? bv0 : g == 1 ? bv1 : g == 2 ? bv2 : bv3;
    float inv = bg[o] / sqrtf(bv[o] + 1e-5f);
    SS[g * 512 + o] = inv;
    SH[g * 512 + o] = (cb[o] - bm[o]) * inv + bb[o];
}

// ---------------- head LIF + transpose: x[t][b][C][196] -> XS[tb*196+n][C] bf16 spikes (compact) ----------------
// grid (4 n-tiles, 32 b, 8 c-groups of 64)
__global__ __launch_bounds__(256) void k_head_lif(const float* __restrict__ x, u16* __restrict__ XS) {
    __shared__ float T[64][65];
    const int tid = threadIdx.x;
    const int n0 = blockIdx.x * 64;       // 0..3 * 64
    const int b  = blockIdx.y;            // 0..31
    const int c_base = blockIdx.z * 64;   // 0..7 * 64
    const int n_l = tid & 63;
    const int c_r0 = tid >> 6;            // 0..3
    const int n_r = tid >> 2;             // 0..63
    const int cq  = (tid & 3) * 16;
    const bool wv = (n0 + n_r) < NN;

    float v[16];
    #pragma unroll
    for (int j = 0; j < 16; ++j) v[j] = 0.f;
    for (int t = 0; t < TT; ++t) {
        const size_t xb = ((size_t)(t * BB + b) * CC + c_base) * NN;
        float s[16];
        #pragma unroll
        for (int j = 0; j < 16; ++j) {
            int c_l = c_r0 + 4 * j;
            float xv = (n0 + n_l < NN) ? x[xb + (size_t)c_l * NN + n0 + n_l] : 0.f;
            float h = v[j] + (xv - v[j]) * 0.5f;
            s[j] = (h >= 1.f) ? 1.f : 0.f;
            v[j] = (h >= 1.f) ? 0.f : h;
        }
        __syncthreads();
        #pragma unroll
        for (int j = 0; j < 16; ++j) T[c_r0 + 4 * j][n_l] = s[j];
        __syncthreads();
        if (wv) {
            const size_t ob = ((size_t)(t * BB + b) * NN + n0 + n_r) * CC + c_base + cq;
            u16 u[16];
            #pragma unroll
            for (int m = 0; m < 16; ++m) u[m] = (T[cq + m][n_r] != 0.f) ? 0x3F80 : 0;
            uint4 q0 = make_uint4(pk2(u[0],u[1]),  pk2(u[2],u[3]),  pk2(u[4],u[5]),  pk2(u[6],u[7]));
            uint4 q1 = make_uint4(pk2(u[8],u[9]),  pk2(u[10],u[11]),pk2(u[12],u[13]),pk2(u[14],u[15]));
            *(uint4*)(XS + ob)     = q0;
            *(uint4*)(XS + ob + 8) = q1;
        }
        __syncthreads();
    }
}

// ---------------- merged QKV MFMA GEMM over compact rows, 3-split bf16 weights ----------------
// LDS layout is k-chunk-major: tile[chunk 0..3][row 0..127][8 u16] so gld16 stays legal
// (LDS dest contiguous per instruction) AND fragment ds_read_b128 is conflict-free
// (bank base = 4*row mod 32 -> 2-way aliasing, free). Old row-major stride 64B was ~8-way.
#define YSTRIDE_F 13631488   // 52MB / 4
__global__ __launch_bounds__(256) void k_gemm_qkv(const u16* __restrict__ S, const u16* __restrict__ W3,
                                                  const float* __restrict__ scale, const float* __restrict__ shift,
                                                  float* __restrict__ Y) {
    __shared__ __align__(16) u16 Xt[4096];        // [4 chunk][128 row][8]
    __shared__ __align__(16) u16 Wt[3][4096];
    const int tid  = threadIdx.x;
    const int lane = tid & 63;
    const int w    = tid >> 6;
    const int bid  = blockIdx.x;
    const int work = (bid & 7) * 294 + (bid >> 3);
    const int ntile = work / 12;          // 0..195
    const int gw    = work - ntile * 12;
    const int g     = gw >> 2;
    const int wtile = gw & 3;
    const u16* Sb = S + (size_t)ntile * 128 * CC;
    const u16* Wb = W3 + (size_t)g * 786432 + (size_t)(wtile * 128) * CC;
    const float* scl = scale + g * 512;
    const float* shf = shift + g * 512;
    float* Yg = Y + (size_t)g * YSTRIDE_F;

    const int l15 = lane & 15;
    const int cid = lane >> 4;           // k-chunk id for fragment reads
    const int wm = (w >> 1) * 64, wn = (w & 1) * 64;

    f32x4 acc[4][4];
    f32x4 zz = {0.f, 0.f, 0.f, 0.f};
    #pragma unroll
    for (int i = 0; i < 4; ++i)
        #pragma unroll
        for (int j = 0; j < 4; ++j) acc[i][j] = zz;

    for (int c0 = 0; c0 < CC; c0 += 32) {
        __syncthreads();
        // spikes: 8 gld16 (2 per wave): (row-half rh, chunk j); lane -> row rh*64+lane
        #pragma unroll
        for (int p2 = 0; p2 < 2; ++p2) {
            int p = w * 2 + p2;          // 0..7
            int rh = p >> 2, j = p & 3;
            gld16(Sb + (size_t)(rh * 64 + lane) * CC + c0 + j * 8, &Xt[j * 1024 + rh * 512]);
        }
        // W: 24 gld16 (6 per wave): (split s, row-half rh, chunk j)
        #pragma unroll
        for (int i = 0; i < 6; ++i) {
            int lin = w * 6 + i;         // 0..23
            int s = lin >> 3, p = lin & 7;
            int rh = p >> 2, j = p & 3;
            gld16(Wb + (size_t)s * 262144 + (size_t)(rh * 64 + lane) * CC + c0 + j * 8,
                  &Wt[s][j * 1024 + rh * 512]);
        }
        __syncthreads();

        bf16x8 sf[4];
        #pragma unroll
        for (int i = 0; i < 4; ++i) sf[i] = *(const bf16x8*)&Xt[cid * 1024 + (wm + i * 16 + l15) * 8];
        #pragma unroll
        for (int s = 0; s < 3; ++s) {
            bf16x8 wf[4];
            #pragma unroll
            for (int i = 0; i < 4; ++i) wf[i] = *(const bf16x8*)&Wt[s][cid * 1024 + (wn + i * 16 + l15) * 8];
            #pragma unroll
            for (int mt = 0; mt < 4; ++mt)
                #pragma unroll
                for (int nt = 0; nt < 4; ++nt)
                    acc[mt][nt] = __builtin_amdgcn_mfma_f32_16x16x32_bf16(sf[mt], wf[nt], acc[mt][nt], 0, 0, 0);
        }
    }

    // epilogue: C/D layout col = lane&15, row = (lane>>4)*4 + reg
    #pragma unroll
    for (int nt = 0; nt < 4; ++nt) {
        int o = wtile * 128 + wn + nt * 16 + l15;
        float sc = scl[o], sh = shf[o];
        #pragma unroll
        for (int mt = 0; mt < 4; ++mt) {
            int r0 = ntile * 128 + wm + mt * 16 + (lane >> 4) * 4;
            #pragma unroll
            for (int r = 0; r < 4; ++r)
                Yg[(size_t)(r0 + r) * CC + o] = acc[mt][nt][r] * sc + sh;
        }
    }
}

// ---------------- merged LIF: q (3 chains) + k + v -> compact bf16 spikes ----------------
__global__ __launch_bounds__(256) void k_lif_all(const float* __restrict__ Yq, const float* __restrict__ Yk,
                                                 const float* __restrict__ Yv, u16* __restrict__ QS,
                                                 u16* __restrict__ KS, u16* __restrict__ VS,
                                                 const float* __restrict__ pw_,
                                                 const float* __restrict__ pl_,
                                                 const float* __restrict__ pb_) {
    size_t idx = (size_t)blockIdx.x * 256 + threadIdx.x;   // flat over one t-slice (3,211,264)
    float pw = log1pf(expf(pw_[0]));
    float pl = log1pf(expf(pl_[0]));
    float pb = pb_[0];
    float von = 0.f, voff = 0.f, vpp = 0.f, vk = 0.f, vv = 0.f;
    #pragma unroll
    for (int t = 0; t < TT; ++t) {
        size_t off = idx + (size_t)t * CSTRIDE;
        float qv = Yq[off], kv = Yk[off], xv = Yv[off];
        float h;
        h = von  + ( qv - von ) * 0.5f; bool s1 = (h >= 1.f); von  = s1 ? 0.f : h;
        h = voff + (-qv - voff) * 0.5f; bool s2 = (h >= 1.f); voff = s2 ? 0.f : h;
        float diff = pw * (s1 ? 1.f : 0.f) - pl * (s2 ? 1.f : 0.f) + pb;
        h = vpp  + (diff - vpp) * 0.5f; bool sp = (h >= 1.f); vpp  = sp ? 0.f : h;
        h = vk   + ( kv - vk  ) * 0.5f; bool sk = (h >= 1.f); vk   = sk ? 0.f : h;
        h = vv   + ( xv - vv  ) * 0.5f; bool sv = (h >= 1.f); vv   = sv ? 0.f : h;
        QS[off] = sp ? 0x3F80 : 0;
        KS[off] = sk ? 0x3F80 : 0;
        VS[off] = sv ? 0x3F80 : 0;
    }
}

// ---------------- MFMA attention per (tb,h): kv = K^T V ; O = 0.125 * Q_pp kv -> bf16 compact ----------------
__global__ __launch_bounds__(256) void k_attn(const u16* __restrict__ Q, const u16* __restrict__ K,
                                              const u16* __restrict__ V, u16* __restrict__ OS) {
    __shared__ __align__(16) u16 sm[19584];   // max(2*64*136, 208*72 + 64*72) u16 = 39168 B
    u16* Kt  = sm;            // phase A: [64 d][136]
    u16* Vt  = sm + 8704;     // phase A: [64 e][136]
    u16* Qs  = sm;            // phase B: [208 n][72]
    u16* kvT = sm + 14976;    // phase B: [64 e][72]

    const int tid = threadIdx.x;
    const int tb  = blockIdx.x >> 3;
    const int h   = blockIdx.x & 7;
    const size_t gb = (size_t)tb * NN * CC + (size_t)h * HD;

    const int srow = tid >> 2;            // 0..63 staging row
    const int sdq  = (tid & 3) * 16;      // 0,16,32,48

    const int lane = tid & 63;
    const int w    = tid >> 6;
    const int l15  = lane & 15;
    const int kb8  = (lane >> 4) * 8;
    const int quad = (lane >> 4) * 4;
    const int dh = (w >> 1) * 32, eh = (w & 1) * 32;

    f32x4 accA[2][2];
    f32x4 zz = {0.f, 0.f, 0.f, 0.f};
    #pragma unroll
    for (int i = 0; i < 2; ++i)
        #pragma unroll
        for (int j = 0; j < 2; ++j) accA[i][j] = zz;

    const uint4 z4 = make_uint4(0, 0, 0, 0);

    // ---- phase A over 2 n-chunks of 128
    #pragma unroll
    for (int ch = 0; ch < 2; ++ch) {
        if (ch) __syncthreads();
        #pragma unroll
        for (int c = 0; c < 2; ++c) {
            int n  = ch * 128 + c * 64 + srow;
            int nl = c * 64 + srow;
            bool valid = n < NN;
            const u16* kr = K + gb + (size_t)n * CC + sdq;
            const u16* vr = V + gb + (size_t)n * CC + sdq;
            uint4 ka  = valid ? *(const uint4*)kr : z4;
            uint4 kb2 = valid ? *(const uint4*)(kr + 8) : z4;
            uint4 va  = valid ? *(const uint4*)vr : z4;
            uint4 vb2 = valid ? *(const uint4*)(vr + 8) : z4;
            u32 kwv[8] = {ka.x, ka.y, ka.z, ka.w, kb2.x, kb2.y, kb2.z, kb2.w};
            u32 vwv[8] = {va.x, va.y, va.z, va.w, vb2.x, vb2.y, vb2.z, vb2.w};
            #pragma unroll
            for (int i = 0; i < 8; ++i) {
                Kt[(sdq + 2 * i) * 136 + nl]     = (u16)(kwv[i] & 0xFFFF);
                Kt[(sdq + 2 * i + 1) * 136 + nl] = (u16)(kwv[i] >> 16);
                Vt[(sdq + 2 * i) * 136 + nl]     = (u16)(vwv[i] & 0xFFFF);
                Vt[(sdq + 2 * i + 1) * 136 + nl] = (u16)(vwv[i] >> 16);
            }
        }
        __syncthreads();
        #pragma unroll
        for (int k0 = 0; k0 < 128; k0 += 32) {
            bf16x8 af[2], bv[2];
            #pragma unroll
            for (int i = 0; i < 2; ++i) {
                af[i] = *(const bf16x8*)&Kt[(dh + i * 16 + l15) * 136 + k0 + kb8];
                bv[i] = *(const bf16x8*)&Vt[(eh + i * 16 + l15) * 136 + k0 + kb8];
            }
            #pragma unroll
            for (int i = 0; i < 2; ++i)
                #pragma unroll
                for (int j = 0; j < 2; ++j)
                    accA[i][j] = __builtin_amdgcn_mfma_f32_16x16x32_bf16(af[i], bv[j], accA[i][j], 0, 0, 0);
        }
    }
    __syncthreads();   // all waves done with Kt/Vt before overwrite

    // ---- write kv^T (bf16, exact: integers <= 196) and stage Q
    #pragma unroll
    for (int i = 0; i < 2; ++i)
        #pragma unroll
        for (int j = 0; j < 2; ++j)
            #pragma unroll
            for (int r = 0; r < 4; ++r) {
                int e = eh + j * 16 + l15;
                int d = dh + i * 16 + quad + r;
                kvT[e * 72 + d] = f2bf(accA[i][j][r]);
            }
    #pragma unroll
    for (int p = 0; p < 4; ++p) {
        int n = p * 64 + srow;
        if (n < 208) {
            if (n < NN) {
                const u16* qr = Q + gb + (size_t)n * CC + sdq;
                uint4 qa  = *(const uint4*)qr;
                uint4 qb2 = *(const uint4*)(qr + 8);
                u32 qwv[8] = {qa.x, qa.y, qa.z, qa.w, qb2.x, qb2.y, qb2.z, qb2.w};
                #pragma unroll
                for (int i = 0; i < 8; ++i) {
                    Qs[n * 72 + sdq + 2 * i]     = (u16)(qwv[i] & 0xFFFF);
                    Qs[n * 72 + sdq + 2 * i + 1] = (u16)(qwv[i] >> 16);
                }
            } else {
                #pragma unroll
                for (int i = 0; i < 16; ++i) Qs[n * 72 + sdq + i] = 0;
            }
        }
    }
    __syncthreads();

    // ---- phase B: wave w owns e-tile [w*16, w*16+16)
    bf16x8 bq0 = *(const bf16x8*)&kvT[(w * 16 + l15) * 72 + 0  + kb8];
    bf16x8 bq1 = *(const bf16x8*)&kvT[(w * 16 + l15) * 72 + 32 + kb8];
    u16* ob = OS + (size_t)tb * NN * CC + (size_t)h * HD + w * 16 + l15;
    #pragma unroll
    for (int nt = 0; nt < 13; ++nt) {
        f32x4 acc = zz;
        bf16x8 a0 = *(const bf16x8*)&Qs[(nt * 16 + l15) * 72 + 0  + kb8];
        bf16x8 a1 = *(const bf16x8*)&Qs[(nt * 16 + l15) * 72 + 32 + kb8];
        acc = __builtin_amdgcn_mfma_f32_16x16x32_bf16(a0, bq0, acc, 0, 0, 0);
        acc = __builtin_amdgcn_mfma_f32_16x16x32_bf16(a1, bq1, acc, 0, 0, 0);
        #pragma unroll
        for (int r = 0; r < 4; ++r) {
            int n = nt * 16 + quad + r;
            if (n < NN) ob[(size_t)n * CC] = f2bf(acc[r] * 0.125f);
        }
    }
}

// ---------------- attn LIF (vth=0.5), compact flat, in place on bf16 ----------------
__global__ __launch_bounds__(256) void k_attn_lif(u16* __restrict__ OS) {
    size_t idx = (size_t)blockIdx.x * 256 + threadIdx.x;   // flat over one t-slice
    float v = 0.f;
    #pragma unroll
    for (int t = 0; t < TT; ++t) {
        size_t off = idx + (size_t)t * CSTRIDE;
        float xv = bf2f(OS[off]);
        float h = v + (xv - v) * 0.5f;
        bool s = (h >= 0.5f);
        v = s ? 0.f : h;
        OS[off] = s ? 0x3F80 : 0;
    }
}

// ---------------- final projection GEMM: out[tb][o][n] = BN(W_p x spikes^T), compact rows ----------------
// 1D grid 784 with XCD-aware swizzle (98 work items per XCD slab). Same chunk-major LDS.
__global__ __launch_bounds__(256) void k_gemm_proj(const u16* __restrict__ S, const u16* __restrict__ W3,
                                                   const float* __restrict__ scale, const float* __restrict__ shift,
                                                   float* __restrict__ Y) {
    __shared__ __align__(16) u16 Xt[4096];
    __shared__ __align__(16) u16 Wt[3][4096];
    const int tid  = threadIdx.x;
    const int lane = tid & 63;
    const int w    = tid >> 6;
    const int bid  = blockIdx.x;
    const int work = (bid & 7) * 98 + (bid >> 3);
    const int ntile = work >> 2;    // 0..195
    const int wtile = work & 3;     // 0..3
    const u16* Sb = S + (size_t)ntile * 128 * CC;
    const u16* Wb = W3 + (size_t)(wtile * 128) * CC;

    const int l15 = lane & 15;
    const int cid = lane >> 4;
    const int wm = (w >> 1) * 64, wn = (w & 1) * 64;

    // a 128-row tile crosses at most one tb boundary
    const int tb0 = (ntile * 128) / NN;
    const int bnd = (tb0 + 1) * NN;

    f32x4 acc[4][4];
    f32x4 zz = {0.f, 0.f, 0.f, 0.f};
    #pragma unroll
    for (int i = 0; i < 4; ++i)
        #pragma unroll
        for (int j = 0; j < 4; ++j) acc[i][j] = zz;

    for (int c0 = 0; c0 < CC; c0 += 32) {
        __syncthreads();
        #pragma unroll
        for (int p2 = 0; p2 < 2; ++p2) {
            int p = w * 2 + p2;
            int rh = p >> 2, j = p & 3;
            gld16(Sb + (size_t)(rh * 64 + lane) * CC + c0 + j * 8, &Xt[j * 1024 + rh * 512]);
        }
        #pragma unroll
        for (int i = 0; i < 6; ++i) {
            int lin = w * 6 + i;
            int s = lin >> 3, p = lin & 7;
            int rh = p >> 2, j = p & 3;
            gld16(Wb + (size_t)s * 262144 + (size_t)(rh * 64 + lane) * CC + c0 + j * 8,
                  &Wt[s][j * 1024 + rh * 512]);
        }
        __syncthreads();

        bf16x8 sf[4];
        #pragma unroll
        for (int i = 0; i < 4; ++i) sf[i] = *(const bf16x8*)&Xt[cid * 1024 + (wn + i * 16 + l15) * 8];
        #pragma unroll
        for (int s = 0; s < 3; ++s) {
            bf16x8 wf[4];
            #pragma unroll
            for (int i = 0; i < 4; ++i) wf[i] = *(const bf16x8*)&Wt[s][cid * 1024 + (wm + i * 16 + l15) * 8];
            #pragma unroll
            for (int mt = 0; mt < 4; ++mt)
                #pragma unroll
                for (int nt = 0; nt < 4; ++nt)
                    acc[mt][nt] = __builtin_amdgcn_mfma_f32_16x16x32_bf16(wf[mt], sf[nt], acc[mt][nt], 0, 0, 0);
        }
    }

    #pragma unroll
    for (int mt = 0; mt < 4; ++mt) {
        int o0 = wtile * 128 + wm + mt * 16 + (lane >> 4) * 4;
        #pragma unroll
        for (int nt = 0; nt < 4; ++nt) {
            int row = ntile * 128 + wn + nt * 16 + l15;
            int tb = (row >= bnd) ? tb0 + 1 : tb0;
            int n  = row - tb * NN;
            #pragma unroll
            for (int r = 0; r < 4; ++r)
                Y[((size_t)tb * CC + o0 + r) * NN + n] = acc[mt][nt][r] * scale[o0 + r] + shift[o0 + r];
        }
    }
}

extern "C" void kernel_launch(void* const* d_in, const int* in_sizes, int n_in,
                              void* d_out, int out_size, void* d_ws, size_t ws_size,
                              hipStream_t stream) {
    const float* x    = (const float*)d_in[0];
    const float* q_cw = (const float*)d_in[1];
    const float* q_cb = (const float*)d_in[2];
    const float* q_bg = (const float*)d_in[3];
    const float* q_bb = (const float*)d_in[4];
    const float* q_bm = (const float*)d_in[5];
    const float* q_bv = (const float*)d_in[6];
    const float* k_cw = (const float*)d_in[7];
    const float* k_cb = (const float*)d_in[8];
    const float* k_bg = (const float*)d_in[9];
    const float* k_bb = (const float*)d_in[10];
    const float* k_bm = (const float*)d_in[11];
    const float* k_bv = (const float*)d_in[12];
    const float* v_cw = (const float*)d_in[13];
    const float* v_cb = (const float*)d_in[14];
    const float* v_bg = (const float*)d_in[15];
    const float* v_bb = (const float*)d_in[16];
    const float* v_bm = (const float*)d_in[17];
    const float* v_bv = (const float*)d_in[18];
    const float* p_cw = (const float*)d_in[19];
    const float* p_cb = (const float*)d_in[20];
    const float* p_bg = (const float*)d_in[21];
    const float* p_bb = (const float*)d_in[22];
    const float* p_bm = (const float*)d_in[23];
    const float* p_bv = (const float*)d_in[24];
    const float* pshw = (const float*)d_in[25];
    const float* pllw = (const float*)d_in[26];
    const float* ppb  = (const float*)d_in[27];
    float* out = (float*)d_out;

    // ws map (compact layouts, 242 MB budget):
    //   [0,26)    XS head spikes (25.7MB); reused as QS after gemm_qkv
    //   [26,78)   Yq fp32 (51.4MB); [26,52) reused as OS after attn inputs consumed
    //   [78,130)  Yk fp32
    //   [130,182) Yv fp32
    //   [182,208) KS ; [208,234) VS
    //   [234,..)  W3 (6MB) + SS/SH
    if (ws_size < (size_t)242 * 1024 * 1024) return;
    char* W = (char*)d_ws;
    u16*   XS = (u16*)W;
    u16*   QS = (u16*)W;
    float* Yq = (float*)(W + ((size_t)26 << 20));
    float* Yk = (float*)(W + ((size_t)78 << 20));
    float* Yv = (float*)(W + ((size_t)130 << 20));
    u16*   KS = (u16*)(W + ((size_t)182 << 20));
    u16*   VS = (u16*)(W + ((size_t)208 << 20));
    u16*   OS = (u16*)(W + ((size_t)26 << 20));   // overwrites Yq (dead after k_lif_all)
    u16*   W3 = (u16*)(W + ((size_t)234 << 20));
    float* SS = (float*)(W + ((size_t)234 << 20) + 6291456);  // scale[4][512]
    float* SH = SS + 2048;                                     // shift[4][512]

    k_prep<<<4104, 256, 0, stream>>>(q_cw, k_cw, v_cw, p_cw,
                                     q_cb, q_bg, q_bb, q_bm, q_bv,
                                     k_cb, k_bg, k_bb, k_bm, k_bv,
                                     v_cb, v_bg, v_bb, v_bm, v_bv,
                                     p_cb, p_bg, p_bb, p_bm, p_bv, W3, SS, SH);

    k_head_lif<<<dim3(4, 32, 8), 256, 0, stream>>>(x, XS);

    // merged Q/K/V projection, XCD-swizzled 1D grid; Yq,Yk,Yv at 52MB stride
    k_gemm_qkv<<<2352, 256, 0, stream>>>(XS, W3, SS, SH, Yq);

    // all 5 LIF chains in one launch -> compact bf16 spikes
    const int validBlocks = (int)(CSTRIDE / 256);   // 12544
    k_lif_all<<<validBlocks, 256, 0, stream>>>(Yq, Yk, Yv, QS, KS, VS, pshw, pllw, ppb);

    k_attn<<<TBB * NHH, 256, 0, stream>>>(QS, KS, VS, OS);
    k_attn_lif<<<validBlocks, 256, 0, stream>>>(OS);

    k_gemm_proj<<<784, 256, 0, stream>>>(OS, W3 + 3 * 786432, SS + 1536, SH + 1536, out);
}

// Round 10
// 406.106 us; speedup vs baseline: 1.2406x; 1.2406x over previous
//
#include <hip/hip_runtime.h>
#include <hip/hip_bf16.h>
#include <math.h>

typedef unsigned short u16;
typedef unsigned int   u32;

#define CC 512
#define NN 196
#define TT 4
#define BB 32
#define TBB 128
#define NHH 8
#define HD 64

// compact-row layout: row = tb*196 + n, M = 128*196 = 25088 rows
#define MROWS   25088
#define ROWS_T  6272                      // rows per t-slice (32*196)
#define CSTRIDE ((size_t)ROWS_T * CC)     // elems per t-slice = 3,211,264

typedef __attribute__((ext_vector_type(8))) short bf16x8;
typedef __attribute__((ext_vector_type(4))) float f32x4;

__device__ __forceinline__ u16 f2bf(float f) {
    __hip_bfloat16 h = __float2bfloat16(f);
    return *(u16*)&h;
}
__device__ __forceinline__ float bf2f(u16 u) {
    u32 ui = ((u32)u) << 16;
    return __uint_as_float(ui);
}
__device__ __forceinline__ u32 pk2(u16 a, u16 b) { return (u32)a | ((u32)b << 16); }

// async 16B/lane global->LDS; lds base must be wave-uniform
__device__ __forceinline__ void gld16(const void* g, void* l) {
    __builtin_amdgcn_global_load_lds(
        (const __attribute__((address_space(1))) void*)g,
        (__attribute__((address_space(3))) void*)l, 16, 0, 0);
}

// ---------------- merged prep: W 3-split (blocks 0..4095) + BN folds (blocks 4096..4103) ----------------
__global__ __launch_bounds__(256) void k_prep(
    const float* __restrict__ qw, const float* __restrict__ kw,
    const float* __restrict__ vw, const float* __restrict__ pw,
    const float* __restrict__ cb0, const float* __restrict__ bg0, const float* __restrict__ bb0,
    const float* __restrict__ bm0, const float* __restrict__ bv0,
    const float* __restrict__ cb1, const float* __restrict__ bg1, const float* __restrict__ bb1,
    const float* __restrict__ bm1, const float* __restrict__ bv1,
    const float* __restrict__ cb2, const float* __restrict__ bg2, const float* __restrict__ bb2,
    const float* __restrict__ bm2, const float* __restrict__ bv2,
    const float* __restrict__ cb3, const float* __restrict__ bg3, const float* __restrict__ bb3,
    const float* __restrict__ bm3, const float* __restrict__ bv3,
    u16* __restrict__ W3, float* __restrict__ SS, float* __restrict__ SH) {
    if (blockIdx.x < 4096) {
        size_t idx = (size_t)blockIdx.x * 256 + threadIdx.x;   // 4 * 262144
        int g = (int)(idx >> 18);
        size_t rem = idx & 262143;
        const float* Ws = (g == 0) ? qw : (g == 1) ? kw : (g == 2) ? vw : pw;
        float w  = Ws[rem];
        u16 u0 = f2bf(w);      float b0 = bf2f(u0);
        float r1 = w - b0;
        u16 u1 = f2bf(r1);     float b1 = bf2f(u1);
        float r2 = r1 - b1;
        u16 u2 = f2bf(r2);
        size_t base = (size_t)g * 786432 + rem;
        W3[base] = u0; W3[base + 262144] = u1; W3[base + 524288] = u2;
        return;
    }
    int idx = (blockIdx.x - 4096) * 256 + threadIdx.x;   // 0..2047
    int g = idx >> 9, o = idx & 511;
    const float* cb = g == 0 ? cb0 : g == 1 ? cb1 : g == 2 ? cb2 : cb3;
    const float* bg = g == 0 ? bg0 : g == 1 ? bg1 : g == 2 ? bg2 : bg3;
    const float* bb = g == 0 ? bb0 : g == 1 ? bb1 : g == 2 ? bb2 : bb3;
    const float* bm = g == 0 ? bm0 : g == 1 ? bm1 : g == 2 ? bm2 : bm3;
    const float* bv = g == 0 ? bv0 : g == 1 ? bv1 : g == 2 ? bv2 : bv3;
    float inv = bg[o] / sqrtf(bv[o] + 1e-5f);
    SS[g * 512 + o] = inv;
    SH[g * 512 + o] = (cb[o] - bm[o]) * inv + bb[o];
}

// ---------------- head LIF + transpose: x[t][b][C][196] -> XS[tb*196+n][C] bf16 spikes (compact) ----------------
// grid (4 n-tiles, 32 b, 8 c-groups of 64)
__global__ __launch_bounds__(256) void k_head_lif(const float* __restrict__ x, u16* __restrict__ XS) {
    __shared__ float T[64][65];
    const int tid = threadIdx.x;
    const int n0 = blockIdx.x * 64;       // 0..3 * 64
    const int b  = blockIdx.y;            // 0..31
    const int c_base = blockIdx.z * 64;   // 0..7 * 64
    const int n_l = tid & 63;
    const int c_r0 = tid >> 6;            // 0..3
    const int n_r = tid >> 2;             // 0..63
    const int cq  = (tid & 3) * 16;
    const bool wv = (n0 + n_r) < NN;

    float v[16];
    #pragma unroll
    for (int j = 0; j < 16; ++j) v[j] = 0.f;
    for (int t = 0; t < TT; ++t) {
        const size_t xb = ((size_t)(t * BB + b) * CC + c_base) * NN;
        float s[16];
        #pragma unroll
        for (int j = 0; j < 16; ++j) {
            int c_l = c_r0 + 4 * j;
            float xv = (n0 + n_l < NN) ? x[xb + (size_t)c_l * NN + n0 + n_l] : 0.f;
            float h = v[j] + (xv - v[j]) * 0.5f;
            s[j] = (h >= 1.f) ? 1.f : 0.f;
            v[j] = (h >= 1.f) ? 0.f : h;
        }
        __syncthreads();
        #pragma unroll
        for (int j = 0; j < 16; ++j) T[c_r0 + 4 * j][n_l] = s[j];
        __syncthreads();
        if (wv) {
            const size_t ob = ((size_t)(t * BB + b) * NN + n0 + n_r) * CC + c_base + cq;
            u16 u[16];
            #pragma unroll
            for (int m = 0; m < 16; ++m) u[m] = (T[cq + m][n_r] != 0.f) ? 0x3F80 : 0;
            uint4 q0 = make_uint4(pk2(u[0],u[1]),  pk2(u[2],u[3]),  pk2(u[4],u[5]),  pk2(u[6],u[7]));
            uint4 q1 = make_uint4(pk2(u[8],u[9]),  pk2(u[10],u[11]),pk2(u[12],u[13]),pk2(u[14],u[15]));
            *(uint4*)(XS + ob)     = q0;
            *(uint4*)(XS + ob + 8) = q1;
        }
        __syncthreads();
    }
}

// ---------------- merged QKV MFMA GEMM over compact rows, 3-split bf16 weights ----------------
// LDS: row-major [128 row][32 u16] with XOR chunk swizzle: physical chunk c of row r holds
// logical chunk c ^ ((r>>1)&3). Staging reads the same full 64B line per row (permuted within
// the line -> global pattern identical to the 134us round-8 kernel), LDS dest stays
// wave-contiguous (gld16-legal), and fragment ds_read_b128 banks are uniform (2 lanes per
// 4-bank group, the b128 minimum -> 0 conflicts).
#define YSTRIDE_F 13631488   // 52MB / 4
__global__ __launch_bounds__(256) void k_gemm_qkv(const u16* __restrict__ S, const u16* __restrict__ W3,
                                                  const float* __restrict__ scale, const float* __restrict__ shift,
                                                  float* __restrict__ Y) {
    __shared__ __align__(16) u16 Xt[128 * 32];
    __shared__ __align__(16) u16 Wt[3][128 * 32];
    const int tid  = threadIdx.x;
    const int lane = tid & 63;
    const int w    = tid >> 6;
    const int bid  = blockIdx.x;
    const int work = (bid & 7) * 294 + (bid >> 3);
    const int ntile = work / 12;          // 0..195
    const int gw    = work - ntile * 12;
    const int g     = gw >> 2;
    const int wtile = gw & 3;
    const u16* Sb = S + (size_t)ntile * 128 * CC;
    const u16* Wb = W3 + (size_t)g * 786432 + (size_t)(wtile * 128) * CC;
    const float* scl = scale + g * 512;
    const float* shf = shift + g * 512;
    float* Yg = Y + (size_t)g * YSTRIDE_F;

    const int lrow   = lane >> 2;                                   // 0..15
    const int lchunk = ((lane & 3) ^ ((lrow >> 1) & 3)) * 8;        // swizzled source chunk
    const int l15 = lane & 15;
    const int kb  = (((lane >> 4) ^ ((l15 >> 1) & 3))) * 8;         // swizzled fragment chunk
    const int wm = (w >> 1) * 64, wn = (w & 1) * 64;

    f32x4 acc[4][4];
    f32x4 zz = {0.f, 0.f, 0.f, 0.f};
    #pragma unroll
    for (int i = 0; i < 4; ++i)
        #pragma unroll
        for (int j = 0; j < 4; ++j) acc[i][j] = zz;

    for (int c0 = 0; c0 < CC; c0 += 32) {
        __syncthreads();
        #pragma unroll
        for (int cpy = 0; cpy < 2; ++cpy) {
            int r = w * 32 + cpy * 16 + lrow;
            gld16(Sb + (size_t)r * CC + c0 + lchunk, &Xt[(w * 32 + cpy * 16) * 32]);
        }
        #pragma unroll
        for (int s = 0; s < 3; ++s)
            #pragma unroll
            for (int cpy = 0; cpy < 2; ++cpy) {
                int r = w * 32 + cpy * 16 + lrow;
                gld16(Wb + (size_t)s * CC * CC + (size_t)r * CC + c0 + lchunk,
                      &Wt[s][(w * 32 + cpy * 16) * 32]);
            }
        __syncthreads();

        bf16x8 sf[4];
        #pragma unroll
        for (int i = 0; i < 4; ++i) sf[i] = *(const bf16x8*)&Xt[(wm + i * 16 + l15) * 32 + kb];
        #pragma unroll
        for (int s = 0; s < 3; ++s) {
            bf16x8 wf[4];
            #pragma unroll
            for (int i = 0; i < 4; ++i) wf[i] = *(const bf16x8*)&Wt[s][(wn + i * 16 + l15) * 32 + kb];
            #pragma unroll
            for (int mt = 0; mt < 4; ++mt)
                #pragma unroll
                for (int nt = 0; nt < 4; ++nt)
                    acc[mt][nt] = __builtin_amdgcn_mfma_f32_16x16x32_bf16(sf[mt], wf[nt], acc[mt][nt], 0, 0, 0);
        }
    }

    // epilogue: C/D layout col = lane&15, row = (lane>>4)*4 + reg
    #pragma unroll
    for (int nt = 0; nt < 4; ++nt) {
        int o = wtile * 128 + wn + nt * 16 + l15;
        float sc = scl[o], sh = shf[o];
        #pragma unroll
        for (int mt = 0; mt < 4; ++mt) {
            int r0 = ntile * 128 + wm + mt * 16 + (lane >> 4) * 4;
            #pragma unroll
            for (int r = 0; r < 4; ++r)
                Yg[(size_t)(r0 + r) * CC + o] = acc[mt][nt][r] * sc + sh;
        }
    }
}

// ---------------- merged LIF: q (3 chains) + k + v -> compact bf16 spikes ----------------
__global__ __launch_bounds__(256) void k_lif_all(const float* __restrict__ Yq, const float* __restrict__ Yk,
                                                 const float* __restrict__ Yv, u16* __restrict__ QS,
                                                 u16* __restrict__ KS, u16* __restrict__ VS,
                                                 const float* __restrict__ pw_,
                                                 const float* __restrict__ pl_,
                                                 const float* __restrict__ pb_) {
    size_t idx = (size_t)blockIdx.x * 256 + threadIdx.x;   // flat over one t-slice (3,211,264)
    float pw = log1pf(expf(pw_[0]));
    float pl = log1pf(expf(pl_[0]));
    float pb = pb_[0];
    float von = 0.f, voff = 0.f, vpp = 0.f, vk = 0.f, vv = 0.f;
    #pragma unroll
    for (int t = 0; t < TT; ++t) {
        size_t off = idx + (size_t)t * CSTRIDE;
        float qv = Yq[off], kv = Yk[off], xv = Yv[off];
        float h;
        h = von  + ( qv - von ) * 0.5f; bool s1 = (h >= 1.f); von  = s1 ? 0.f : h;
        h = voff + (-qv - voff) * 0.5f; bool s2 = (h >= 1.f); voff = s2 ? 0.f : h;
        float diff = pw * (s1 ? 1.f : 0.f) - pl * (s2 ? 1.f : 0.f) + pb;
        h = vpp  + (diff - vpp) * 0.5f; bool sp = (h >= 1.f); vpp  = sp ? 0.f : h;
        h = vk   + ( kv - vk  ) * 0.5f; bool sk = (h >= 1.f); vk   = sk ? 0.f : h;
        h = vv   + ( xv - vv  ) * 0.5f; bool sv = (h >= 1.f); vv   = sv ? 0.f : h;
        QS[off] = sp ? 0x3F80 : 0;
        KS[off] = sk ? 0x3F80 : 0;
        VS[off] = sv ? 0x3F80 : 0;
    }
}

// ---------------- MFMA attention per (tb,h): kv = K^T V ; O = 0.125 * Q_pp kv -> bf16 compact ----------------
__global__ __launch_bounds__(256) void k_attn(const u16* __restrict__ Q, const u16* __restrict__ K,
                                              const u16* __restrict__ V, u16* __restrict__ OS) {
    __shared__ __align__(16) u16 sm[19584];   // max(2*64*136, 208*72 + 64*72) u16 = 39168 B
    u16* Kt  = sm;            // phase A: [64 d][136]
    u16* Vt  = sm + 8704;     // phase A: [64 e][136]
    u16* Qs  = sm;            // phase B: [208 n][72]
    u16* kvT = sm + 14976;    // phase B: [64 e][72]

    const int tid = threadIdx.x;
    const int tb  = blockIdx.x >> 3;
    const int h   = blockIdx.x & 7;
    const size_t gb = (size_t)tb * NN * CC + (size_t)h * HD;

    const int srow = tid >> 2;            // 0..63 staging row
    const int sdq  = (tid & 3) * 16;      // 0,16,32,48

    const int lane = tid & 63;
    const int w    = tid >> 6;
    const int l15  = lane & 15;
    const int kb8  = (lane >> 4) * 8;
    const int quad = (lane >> 4) * 4;
    const int dh = (w >> 1) * 32, eh = (w & 1) * 32;

    f32x4 accA[2][2];
    f32x4 zz = {0.f, 0.f, 0.f, 0.f};
    #pragma unroll
    for (int i = 0; i < 2; ++i)
        #pragma unroll
        for (int j = 0; j < 2; ++j) accA[i][j] = zz;

    const uint4 z4 = make_uint4(0, 0, 0, 0);

    // ---- phase A over 2 n-chunks of 128
    #pragma unroll
    for (int ch = 0; ch < 2; ++ch) {
        if (ch) __syncthreads();
        #pragma unroll
        for (int c = 0; c < 2; ++c) {
            int n  = ch * 128 + c * 64 + srow;
            int nl = c * 64 + srow;
            bool valid = n < NN;
            const u16* kr = K + gb + (size_t)n * CC + sdq;
            const u16* vr = V + gb + (size_t)n * CC + sdq;
            uint4 ka  = valid ? *(const uint4*)kr : z4;
            uint4 kb2 = valid ? *(const uint4*)(kr + 8) : z4;
            uint4 va  = valid ? *(const uint4*)vr : z4;
            uint4 vb2 = valid ? *(const uint4*)(vr + 8) : z4;
            u32 kwv[8] = {ka.x, ka.y, ka.z, ka.w, kb2.x, kb2.y, kb2.z, kb2.w};
            u32 vwv[8] = {va.x, va.y, va.z, va.w, vb2.x, vb2.y, vb2.z, vb2.w};
            #pragma unroll
            for (int i = 0; i < 8; ++i) {
                Kt[(sdq + 2 * i) * 136 + nl]     = (u16)(kwv[i] & 0xFFFF);
                Kt[(sdq + 2 * i + 1) * 136 + nl] = (u16)(kwv[i] >> 16);
                Vt[(sdq + 2 * i) * 136 + nl]     = (u16)(vwv[i] & 0xFFFF);
                Vt[(sdq + 2 * i + 1) * 136 + nl] = (u16)(vwv[i] >> 16);
            }
        }
        __syncthreads();
        #pragma unroll
        for (int k0 = 0; k0 < 128; k0 += 32) {
            bf16x8 af[2], bv[2];
            #pragma unroll
            for (int i = 0; i < 2; ++i) {
                af[i] = *(const bf16x8*)&Kt[(dh + i * 16 + l15) * 136 + k0 + kb8];
                bv[i] = *(const bf16x8*)&Vt[(eh + i * 16 + l15) * 136 + k0 + kb8];
            }
            #pragma unroll
            for (int i = 0; i < 2; ++i)
                #pragma unroll
                for (int j = 0; j < 2; ++j)
                    accA[i][j] = __builtin_amdgcn_mfma_f32_16x16x32_bf16(af[i], bv[j], accA[i][j], 0, 0, 0);
        }
    }
    __syncthreads();   // all waves done with Kt/Vt before overwrite

    // ---- write kv^T (bf16, exact: integers <= 196) and stage Q
    #pragma unroll
    for (int i = 0; i < 2; ++i)
        #pragma unroll
        for (int j = 0; j < 2; ++j)
            #pragma unroll
            for (int r = 0; r < 4; ++r) {
                int e = eh + j * 16 + l15;
                int d = dh + i * 16 + quad + r;
                kvT[e * 72 + d] = f2bf(accA[i][j][r]);
            }
    #pragma unroll
    for (int p = 0; p < 4; ++p) {
        int n = p * 64 + srow;
        if (n < 208) {
            if (n < NN) {
                const u16* qr = Q + gb + (size_t)n * CC + sdq;
                uint4 qa  = *(const uint4*)qr;
                uint4 qb2 = *(const uint4*)(qr + 8);
                u32 qwv[8] = {qa.x, qa.y, qa.z, qa.w, qb2.x, qb2.y, qb2.z, qb2.w};
                #pragma unroll
                for (int i = 0; i < 8; ++i) {
                    Qs[n * 72 + sdq + 2 * i]     = (u16)(qwv[i] & 0xFFFF);
                    Qs[n * 72 + sdq + 2 * i + 1] = (u16)(qwv[i] >> 16);
                }
            } else {
                #pragma unroll
                for (int i = 0; i < 16; ++i) Qs[n * 72 + sdq + i] = 0;
            }
        }
    }
    __syncthreads();

    // ---- phase B: wave w owns e-tile [w*16, w*16+16)
    bf16x8 bq0 = *(const bf16x8*)&kvT[(w * 16 + l15) * 72 + 0  + kb8];
    bf16x8 bq1 = *(const bf16x8*)&kvT[(w * 16 + l15) * 72 + 32 + kb8];
    u16* ob = OS + (size_t)tb * NN * CC + (size_t)h * HD + w * 16 + l15;
    #pragma unroll
    for (int nt = 0; nt < 13; ++nt) {
        f32x4 acc = zz;
        bf16x8 a0 = *(const bf16x8*)&Qs[(nt * 16 + l15) * 72 + 0  + kb8];
        bf16x8 a1 = *(const bf16x8*)&Qs[(nt * 16 + l15) * 72 + 32 + kb8];
        acc = __builtin_amdgcn_mfma_f32_16x16x32_bf16(a0, bq0, acc, 0, 0, 0);
        acc = __builtin_amdgcn_mfma_f32_16x16x32_bf16(a1, bq1, acc, 0, 0, 0);
        #pragma unroll
        for (int r = 0; r < 4; ++r) {
            int n = nt * 16 + quad + r;
            if (n < NN) ob[(size_t)n * CC] = f2bf(acc[r] * 0.125f);
        }
    }
}

// ---------------- attn LIF (vth=0.5), compact flat, in place on bf16 ----------------
__global__ __launch_bounds__(256) void k_attn_lif(u16* __restrict__ OS) {
    size_t idx = (size_t)blockIdx.x * 256 + threadIdx.x;   // flat over one t-slice
    float v = 0.f;
    #pragma unroll
    for (int t = 0; t < TT; ++t) {
        size_t off = idx + (size_t)t * CSTRIDE;
        float xv = bf2f(OS[off]);
        float h = v + (xv - v) * 0.5f;
        bool s = (h >= 0.5f);
        v = s ? 0.f : h;
        OS[off] = s ? 0x3F80 : 0;
    }
}

// ---------------- final projection GEMM: out[tb][o][n] = BN(W_p x spikes^T), compact rows ----------------
// 1D grid 784 with XCD-aware swizzle (98 work items per XCD slab). Same XOR-swizzled LDS.
__global__ __launch_bounds__(256) void k_gemm_proj(const u16* __restrict__ S, const u16* __restrict__ W3,
                                                   const float* __restrict__ scale, const float* __restrict__ shift,
                                                   float* __restrict__ Y) {
    __shared__ __align__(16) u16 Xt[128 * 32];
    __shared__ __align__(16) u16 Wt[3][128 * 32];
    const int tid  = threadIdx.x;
    const int lane = tid & 63;
    const int w    = tid >> 6;
    const int bid  = blockIdx.x;
    const int work = (bid & 7) * 98 + (bid >> 3);
    const int ntile = work >> 2;    // 0..195
    const int wtile = work & 3;     // 0..3
    const u16* Sb = S + (size_t)ntile * 128 * CC;
    const u16* Wb = W3 + (size_t)(wtile * 128) * CC;

    const int lrow   = lane >> 2;
    const int lchunk = ((lane & 3) ^ ((lrow >> 1) & 3)) * 8;
    const int l15 = lane & 15;
    const int kb  = (((lane >> 4) ^ ((l15 >> 1) & 3))) * 8;
    const int wm = (w >> 1) * 64, wn = (w & 1) * 64;

    // a 128-row tile crosses at most one tb boundary
    const int tb0 = (ntile * 128) / NN;
    const int bnd = (tb0 + 1) * NN;

    f32x4 acc[4][4];
    f32x4 zz = {0.f, 0.f, 0.f, 0.f};
    #pragma unroll
    for (int i = 0; i < 4; ++i)
        #pragma unroll
        for (int j = 0; j < 4; ++j) acc[i][j] = zz;

    for (int c0 = 0; c0 < CC; c0 += 32) {
        __syncthreads();
        #pragma unroll
        for (int cpy = 0; cpy < 2; ++cpy) {
            int r = w * 32 + cpy * 16 + lrow;
            gld16(Sb + (size_t)r * CC + c0 + lchunk, &Xt[(w * 32 + cpy * 16) * 32]);
        }
        #pragma unroll
        for (int s = 0; s < 3; ++s)
            #pragma unroll
            for (int cpy = 0; cpy < 2; ++cpy) {
                int r = w * 32 + cpy * 16 + lrow;
                gld16(Wb + (size_t)s * CC * CC + (size_t)r * CC + c0 + lchunk,
                      &Wt[s][(w * 32 + cpy * 16) * 32]);
            }
        __syncthreads();

        bf16x8 sf[4];
        #pragma unroll
        for (int i = 0; i < 4; ++i) sf[i] = *(const bf16x8*)&Xt[(wn + i * 16 + l15) * 32 + kb];
        #pragma unroll
        for (int s = 0; s < 3; ++s) {
            bf16x8 wf[4];
            #pragma unroll
            for (int i = 0; i < 4; ++i) wf[i] = *(const bf16x8*)&Wt[s][(wm + i * 16 + l15) * 32 + kb];
            #pragma unroll
            for (int mt = 0; mt < 4; ++mt)
                #pragma unroll
                for (int nt = 0; nt < 4; ++nt)
                    acc[mt][nt] = __builtin_amdgcn_mfma_f32_16x16x32_bf16(wf[mt], sf[nt], acc[mt][nt], 0, 0, 0);
        }
    }

    #pragma unroll
    for (int mt = 0; mt < 4; ++mt) {
        int o0 = wtile * 128 + wm + mt * 16 + (lane >> 4) * 4;
        #pragma unroll
        for (int nt = 0; nt < 4; ++nt) {
            int row = ntile * 128 + wn + nt * 16 + l15;
            int tb = (row >= bnd) ? tb0 + 1 : tb0;
            int n  = row - tb * NN;
            #pragma unroll
            for (int r = 0; r < 4; ++r)
                Y[((size_t)tb * CC + o0 + r) * NN + n] = acc[mt][nt][r] * scale[o0 + r] + shift[o0 + r];
        }
    }
}

extern "C" void kernel_launch(void* const* d_in, const int* in_sizes, int n_in,
                              void* d_out, int out_size, void* d_ws, size_t ws_size,
                              hipStream_t stream) {
    const float* x    = (const float*)d_in[0];
    const float* q_cw = (const float*)d_in[1];
    const float* q_cb = (const float*)d_in[2];
    const float* q_bg = (const float*)d_in[3];
    const float* q_bb = (const float*)d_in[4];
    const float* q_bm = (const float*)d_in[5];
    const float* q_bv = (const float*)d_in[6];
    const float* k_cw = (const float*)d_in[7];
    const float* k_cb = (const float*)d_in[8];
    const float* k_bg = (const float*)d_in[9];
    const float* k_bb = (const float*)d_in[10];
    const float* k_bm = (const float*)d_in[11];
    const float* k_bv = (const float*)d_in[12];
    const float* v_cw = (const float*)d_in[13];
    const float* v_cb = (const float*)d_in[14];
    const float* v_bg = (const float*)d_in[15];
    const float* v_bb = (const float*)d_in[16];
    const float* v_bm = (const float*)d_in[17];
    const float* v_bv = (const float*)d_in[18];
    const float* p_cw = (const float*)d_in[19];
    const float* p_cb = (const float*)d_in[20];
    const float* p_bg = (const float*)d_in[21];
    const float* p_bb = (const float*)d_in[22];
    const float* p_bm = (const float*)d_in[23];
    const float* p_bv = (const float*)d_in[24];
    const float* pshw = (const float*)d_in[25];
    const float* pllw = (const float*)d_in[26];
    const float* ppb  = (const float*)d_in[27];
    float* out = (float*)d_out;

    // ws map (compact layouts, 242 MB budget):
    //   [0,26)    XS head spikes (25.7MB); reused as QS after gemm_qkv
    //   [26,78)   Yq fp32 (51.4MB); [26,52) reused as OS after attn inputs consumed
    //   [78,130)  Yk fp32
    //   [130,182) Yv fp32
    //   [182,208) KS ; [208,234) VS
    //   [234,..)  W3 (6MB) + SS/SH
    if (ws_size < (size_t)242 * 1024 * 1024) return;
    char* W = (char*)d_ws;
    u16*   XS = (u16*)W;
    u16*   QS = (u16*)W;
    float* Yq = (float*)(W + ((size_t)26 << 20));
    float* Yk = (float*)(W + ((size_t)78 << 20));
    float* Yv = (float*)(W + ((size_t)130 << 20));
    u16*   KS = (u16*)(W + ((size_t)182 << 20));
    u16*   VS = (u16*)(W + ((size_t)208 << 20));
    u16*   OS = (u16*)(W + ((size_t)26 << 20));   // overwrites Yq (dead after k_lif_all)
    u16*   W3 = (u16*)(W + ((size_t)234 << 20));
    float* SS = (float*)(W + ((size_t)234 << 20) + 6291456);  // scale[4][512]
    float* SH = SS + 2048;                                     // shift[4][512]

    k_prep<<<4104, 256, 0, stream>>>(q_cw, k_cw, v_cw, p_cw,
                                     q_cb, q_bg, q_bb, q_bm, q_bv,
                                     k_cb, k_bg, k_bb, k_bm, k_bv,
                                     v_cb, v_bg, v_bb, v_bm, v_bv,
                                     p_cb, p_bg, p_bb, p_bm, p_bv, W3, SS, SH);

    k_head_lif<<<dim3(4, 32, 8), 256, 0, stream>>>(x, XS);

    // merged Q/K/V projection, XCD-swizzled 1D grid; Yq,Yk,Yv at 52MB stride
    k_gemm_qkv<<<2352, 256, 0, stream>>>(XS, W3, SS, SH, Yq);

    // all 5 LIF chains in one launch -> compact bf16 spikes
    const int validBlocks = (int)(CSTRIDE / 256);   // 12544
    k_lif_all<<<validBlocks, 256, 0, stream>>>(Yq, Yk, Yv, QS, KS, VS, pshw, pllw, ppb);

    k_attn<<<TBB * NHH, 256, 0, stream>>>(QS, KS, VS, OS);
    k_attn_lif<<<validBlocks, 256, 0, stream>>>(OS);

    k_gemm_proj<<<784, 256, 0, stream>>>(OS, W3 + 3 * 786432, SS + 1536, SH + 1536, out);
}

// Round 11
// 351.140 us; speedup vs baseline: 1.4348x; 1.1565x over previous
//
#include <hip/hip_runtime.h>
#include <hip/hip_bf16.h>
#include <math.h>

typedef unsigned short u16;
typedef unsigned int   u32;

#define CC 512
#define NN 196
#define TT 4
#define BB 32
#define TBB 128
#define NHH 8
#define HD 64

// compact-row layout: row = tb*196 + n, M = 128*196 = 25088 rows
#define ROWS_T  6272                      // rows per t-slice (32*196)
#define CSTRIDE ((size_t)ROWS_T * CC)     // elems per t-slice = 3,211,264

typedef __attribute__((ext_vector_type(8))) _Float16 f16x8;
typedef __attribute__((ext_vector_type(4))) float f32x4;

#define ONE_H 0x3C00            // fp16 1.0

__device__ __forceinline__ u16 h_bits(_Float16 h) { return *(u16*)&h; }
__device__ __forceinline__ float h2f(u16 u) { return (float)(*(const _Float16*)&u); }
__device__ __forceinline__ u32 pk2(u16 a, u16 b) { return (u32)a | ((u32)b << 16); }

// async 16B/lane global->LDS; lds base must be wave-uniform
__device__ __forceinline__ void gld16(const void* g, void* l) {
    __builtin_amdgcn_global_load_lds(
        (const __attribute__((address_space(1))) void*)g,
        (__attribute__((address_space(3))) void*)l, 16, 0, 0);
}

// ---------------- merged prep: W 2-plane fp16 split (blocks 0..4095) + BN folds (4096..4103) ----------------
// w = h0 + h1/2048 with residual <= |w|*2^-22 (y-noise ~1e-7, below fp32 accum noise).
// h0 forced to 0 below fp16 min-normal so no MFMA-input subnormals matter.
__global__ __launch_bounds__(256) void k_prep(
    const float* __restrict__ qw, const float* __restrict__ kw,
    const float* __restrict__ vw, const float* __restrict__ pw,
    const float* __restrict__ cb0, const float* __restrict__ bg0, const float* __restrict__ bb0,
    const float* __restrict__ bm0, const float* __restrict__ bv0,
    const float* __restrict__ cb1, const float* __restrict__ bg1, const float* __restrict__ bb1,
    const float* __restrict__ bm1, const float* __restrict__ bv1,
    const float* __restrict__ cb2, const float* __restrict__ bg2, const float* __restrict__ bb2,
    const float* __restrict__ bm2, const float* __restrict__ bv2,
    const float* __restrict__ cb3, const float* __restrict__ bg3, const float* __restrict__ bb3,
    const float* __restrict__ bm3, const float* __restrict__ bv3,
    u16* __restrict__ W2, float* __restrict__ SS, float* __restrict__ SH) {
    if (blockIdx.x < 4096) {
        size_t idx = (size_t)blockIdx.x * 256 + threadIdx.x;   // 4 * 262144
        int g = (int)(idx >> 18);
        size_t rem = idx & 262143;
        const float* Ws = (g == 0) ? qw : (g == 1) ? kw : (g == 2) ? vw : pw;
        float w  = Ws[rem];
        _Float16 h0 = (fabsf(w) < 6.2e-5f) ? (_Float16)0.0f : (_Float16)w;
        float r = (w - (float)h0) * 2048.0f;   // exact; |r| <= |w| -> fp16-normal range
        _Float16 h1 = (_Float16)r;
        size_t base = (size_t)g * 524288 + rem;
        W2[base] = h_bits(h0); W2[base + 262144] = h_bits(h1);
        return;
    }
    int idx = (blockIdx.x - 4096) * 256 + threadIdx.x;   // 0..2047
    int g = idx >> 9, o = idx & 511;
    const float* cb = g == 0 ? cb0 : g == 1 ? cb1 : g == 2 ? cb2 : cb3;
    const float* bg = g == 0 ? bg0 : g == 1 ? bg1 : g == 2 ? bg2 : bg3;
    const float* bb = g == 0 ? bb0 : g == 1 ? bb1 : g == 2 ? bb2 : bb3;
    const float* bm = g == 0 ? bm0 : g == 1 ? bm1 : g == 2 ? bm2 : bm3;
    const float* bv = g == 0 ? bv0 : g == 1 ? bv1 : g == 2 ? bv2 : bv3;
    float inv = bg[o] / sqrtf(bv[o] + 1e-5f);
    SS[g * 512 + o] = inv;
    SH[g * 512 + o] = (cb[o] - bm[o]) * inv + bb[o];
}

// ---------------- head LIF + transpose: x[t][b][C][196] -> XS[tb*196+n][C] fp16 spikes (compact) ----------------
__global__ __launch_bounds__(256) void k_head_lif(const float* __restrict__ x, u16* __restrict__ XS) {
    __shared__ float T[64][65];
    const int tid = threadIdx.x;
    const int n0 = blockIdx.x * 64;       // 0..3 * 64
    const int b  = blockIdx.y;            // 0..31
    const int c_base = blockIdx.z * 64;   // 0..7 * 64
    const int n_l = tid & 63;
    const int c_r0 = tid >> 6;            // 0..3
    const int n_r = tid >> 2;             // 0..63
    const int cq  = (tid & 3) * 16;
    const bool wv = (n0 + n_r) < NN;

    float v[16];
    #pragma unroll
    for (int j = 0; j < 16; ++j) v[j] = 0.f;
    for (int t = 0; t < TT; ++t) {
        const size_t xb = ((size_t)(t * BB + b) * CC + c_base) * NN;
        float s[16];
        #pragma unroll
        for (int j = 0; j < 16; ++j) {
            int c_l = c_r0 + 4 * j;
            float xv = (n0 + n_l < NN) ? x[xb + (size_t)c_l * NN + n0 + n_l] : 0.f;
            float h = v[j] + (xv - v[j]) * 0.5f;
            s[j] = (h >= 1.f) ? 1.f : 0.f;
            v[j] = (h >= 1.f) ? 0.f : h;
        }
        __syncthreads();
        #pragma unroll
        for (int j = 0; j < 16; ++j) T[c_r0 + 4 * j][n_l] = s[j];
        __syncthreads();
        if (wv) {
            const size_t ob = ((size_t)(t * BB + b) * NN + n0 + n_r) * CC + c_base + cq;
            u16 u[16];
            #pragma unroll
            for (int m = 0; m < 16; ++m) u[m] = (T[cq + m][n_r] != 0.f) ? ONE_H : 0;
            uint4 q0 = make_uint4(pk2(u[0],u[1]),  pk2(u[2],u[3]),  pk2(u[4],u[5]),  pk2(u[6],u[7]));
            uint4 q1 = make_uint4(pk2(u[8],u[9]),  pk2(u[10],u[11]),pk2(u[12],u[13]),pk2(u[14],u[15]));
            *(uint4*)(XS + ob)     = q0;
            *(uint4*)(XS + ob + 8) = q1;
        }
        __syncthreads();
    }
}

// ---------------- merged QKV MFMA GEMM, 2-plane fp16, BK=64 ----------------
// LDS [128 row][64 fp16] (128B rows) with XOR-7 chunk swizzle: physical 16B-chunk c of row r
// holds logical chunk c ^ (r&7). Staging: 8 lanes cover one full 128B row (2 dense lines,
// permuted within) -> gld16-legal + line-dense. Fragment ds_read_b128: bank group = phys
// chunk, each 16-lane quarter spreads over all 8 groups x2 -> conflict-free.
// Plane1 accumulates into the SAME fp32 acc via spike-side 2^-11 scaling (sf_lo = sf*2^-11):
// product s*2^-11 * (w-h0)*2048 = s*(w-h0) exactly.
#define YSTRIDE_F 13631488   // 52MB / 4
__global__ __launch_bounds__(256) void k_gemm_qkv(const u16* __restrict__ S, const u16* __restrict__ W2,
                                                  const float* __restrict__ scale, const float* __restrict__ shift,
                                                  float* __restrict__ Y) {
    __shared__ __align__(16) u16 Xt[128 * 64];      // 16 KB
    __shared__ __align__(16) u16 Wt[2][128 * 64];   // 32 KB
    const int tid  = threadIdx.x;
    const int lane = tid & 63;
    const int w    = tid >> 6;
    const int bid  = blockIdx.x;
    const int work = (bid & 7) * 294 + (bid >> 3);
    const int ntile = work / 12;          // 0..195
    const int gw    = work - ntile * 12;
    const int g     = gw >> 2;
    const int wtile = gw & 3;
    const u16* Sb = S + (size_t)ntile * 128 * CC;
    const u16* Wb = W2 + (size_t)g * 524288 + (size_t)(wtile * 128) * CC;
    const float* scl = scale + g * 512;
    const float* shf = shift + g * 512;
    float* Yg = Y + (size_t)g * YSTRIDE_F;

    const int lrow8  = lane >> 3;                    // 0..7 (staging row within 8)
    const int gchunk = ((lane & 7) ^ lrow8) * 8;     // swizzled logical chunk (elems)
    const int l15 = lane & 15;
    const int q4  = lane >> 4;                       // 0..3
    const int wm = (w >> 1) * 64, wn = (w & 1) * 64;

    f32x4 acc[4][4];
    f32x4 zz = {0.f, 0.f, 0.f, 0.f};
    #pragma unroll
    for (int i = 0; i < 4; ++i)
        #pragma unroll
        for (int j = 0; j < 4; ++j) acc[i][j] = zz;

    for (int c0 = 0; c0 < CC; c0 += 64) {
        __syncthreads();
        #pragma unroll
        for (int i = 0; i < 4; ++i) {                // spikes: 16 instrs (4/wave)
            int p = w * 4 + i;                       // 0..15 -> rows p*8..p*8+7
            gld16(Sb + (size_t)(p * 8 + lrow8) * CC + c0 + gchunk, &Xt[p * 512]);
        }
        #pragma unroll
        for (int i = 0; i < 8; ++i) {                // W: 32 instrs (8/wave)
            int lin = w * 8 + i;                     // 0..31
            int s = lin >> 4, p = lin & 15;
            gld16(Wb + (size_t)s * 262144 + (size_t)(p * 8 + lrow8) * CC + c0 + gchunk,
                  &Wt[s][p * 512]);
        }
        __syncthreads();

        #pragma unroll
        for (int ks = 0; ks < 2; ++ks) {
            const int cpo = ((ks * 4 + q4) ^ (l15 & 7)) * 8;
            f16x8 sf[4], sflo[4];
            #pragma unroll
            for (int i = 0; i < 4; ++i) {
                sf[i]   = *(const f16x8*)&Xt[(wm + i * 16 + l15) * 64 + cpo];
                sflo[i] = sf[i] * (_Float16)0.00048828125f;   // 2^-11
            }
            #pragma unroll
            for (int s = 0; s < 2; ++s) {
                f16x8 wf[4];
                #pragma unroll
                for (int i = 0; i < 4; ++i)
                    wf[i] = *(const f16x8*)&Wt[s][(wn + i * 16 + l15) * 64 + cpo];
                #pragma unroll
                for (int mt = 0; mt < 4; ++mt)
                    #pragma unroll
                    for (int nt = 0; nt < 4; ++nt)
                        acc[mt][nt] = __builtin_amdgcn_mfma_f32_16x16x32_f16(
                            s ? sflo[mt] : sf[mt], wf[nt], acc[mt][nt], 0, 0, 0);
            }
        }
    }

    // epilogue: C/D layout col = lane&15, row = (lane>>4)*4 + reg
    #pragma unroll
    for (int nt = 0; nt < 4; ++nt) {
        int o = wtile * 128 + wn + nt * 16 + l15;
        float sc = scl[o], sh = shf[o];
        #pragma unroll
        for (int mt = 0; mt < 4; ++mt) {
            int r0 = ntile * 128 + wm + mt * 16 + (lane >> 4) * 4;
            #pragma unroll
            for (int r = 0; r < 4; ++r)
                Yg[(size_t)(r0 + r) * CC + o] = acc[mt][nt][r] * sc + sh;
        }
    }
}

// ---------------- merged LIF: q (3 chains) + k + v -> compact fp16 spikes ----------------
__global__ __launch_bounds__(256) void k_lif_all(const float* __restrict__ Yq, const float* __restrict__ Yk,
                                                 const float* __restrict__ Yv, u16* __restrict__ QS,
                                                 u16* __restrict__ KS, u16* __restrict__ VS,
                                                 const float* __restrict__ pw_,
                                                 const float* __restrict__ pl_,
                                                 const float* __restrict__ pb_) {
    size_t idx = (size_t)blockIdx.x * 256 + threadIdx.x;   // flat over one t-slice (3,211,264)
    float pw = log1pf(expf(pw_[0]));
    float pl = log1pf(expf(pl_[0]));
    float pb = pb_[0];
    float von = 0.f, voff = 0.f, vpp = 0.f, vk = 0.f, vv = 0.f;
    #pragma unroll
    for (int t = 0; t < TT; ++t) {
        size_t off = idx + (size_t)t * CSTRIDE;
        float qv = Yq[off], kv = Yk[off], xv = Yv[off];
        float h;
        h = von  + ( qv - von ) * 0.5f; bool s1 = (h >= 1.f); von  = s1 ? 0.f : h;
        h = voff + (-qv - voff) * 0.5f; bool s2 = (h >= 1.f); voff = s2 ? 0.f : h;
        float diff = pw * (s1 ? 1.f : 0.f) - pl * (s2 ? 1.f : 0.f) + pb;
        h = vpp  + (diff - vpp) * 0.5f; bool sp = (h >= 1.f); vpp  = sp ? 0.f : h;
        h = vk   + ( kv - vk  ) * 0.5f; bool sk = (h >= 1.f); vk   = sk ? 0.f : h;
        h = vv   + ( xv - vv  ) * 0.5f; bool sv = (h >= 1.f); vv   = sv ? 0.f : h;
        QS[off] = sp ? ONE_H : 0;
        KS[off] = sk ? ONE_H : 0;
        VS[off] = sv ? ONE_H : 0;
    }
}

// ---------------- MFMA attention per (tb,h): kv = K^T V ; O = 0.125 * Q_pp kv -> fp16 compact ----------------
__global__ __launch_bounds__(256) void k_attn(const u16* __restrict__ Q, const u16* __restrict__ K,
                                              const u16* __restrict__ V, u16* __restrict__ OS) {
    __shared__ __align__(16) u16 sm[19584];   // max(2*64*136, 208*72 + 64*72) u16 = 39168 B
    u16* Kt  = sm;            // phase A: [64 d][136]
    u16* Vt  = sm + 8704;     // phase A: [64 e][136]
    u16* Qs  = sm;            // phase B: [208 n][72]
    u16* kvT = sm + 14976;    // phase B: [64 e][72]

    const int tid = threadIdx.x;
    const int tb  = blockIdx.x >> 3;
    const int h   = blockIdx.x & 7;
    const size_t gb = (size_t)tb * NN * CC + (size_t)h * HD;

    const int srow = tid >> 2;            // 0..63 staging row
    const int sdq  = (tid & 3) * 16;      // 0,16,32,48

    const int lane = tid & 63;
    const int w    = tid >> 6;
    const int l15  = lane & 15;
    const int kb8  = (lane >> 4) * 8;
    const int quad = (lane >> 4) * 4;
    const int dh = (w >> 1) * 32, eh = (w & 1) * 32;

    f32x4 accA[2][2];
    f32x4 zz = {0.f, 0.f, 0.f, 0.f};
    #pragma unroll
    for (int i = 0; i < 2; ++i)
        #pragma unroll
        for (int j = 0; j < 2; ++j) accA[i][j] = zz;

    const uint4 z4 = make_uint4(0, 0, 0, 0);

    // ---- phase A over 2 n-chunks of 128
    #pragma unroll
    for (int ch = 0; ch < 2; ++ch) {
        if (ch) __syncthreads();
        #pragma unroll
        for (int c = 0; c < 2; ++c) {
            int n  = ch * 128 + c * 64 + srow;
            int nl = c * 64 + srow;
            bool valid = n < NN;
            const u16* kr = K + gb + (size_t)n * CC + sdq;
            const u16* vr = V + gb + (size_t)n * CC + sdq;
            uint4 ka  = valid ? *(const uint4*)kr : z4;
            uint4 kb2 = valid ? *(const uint4*)(kr + 8) : z4;
            uint4 va  = valid ? *(const uint4*)vr : z4;
            uint4 vb2 = valid ? *(const uint4*)(vr + 8) : z4;
            u32 kwv[8] = {ka.x, ka.y, ka.z, ka.w, kb2.x, kb2.y, kb2.z, kb2.w};
            u32 vwv[8] = {va.x, va.y, va.z, va.w, vb2.x, vb2.y, vb2.z, vb2.w};
            #pragma unroll
            for (int i = 0; i < 8; ++i) {
                Kt[(sdq + 2 * i) * 136 + nl]     = (u16)(kwv[i] & 0xFFFF);
                Kt[(sdq + 2 * i + 1) * 136 + nl] = (u16)(kwv[i] >> 16);
                Vt[(sdq + 2 * i) * 136 + nl]     = (u16)(vwv[i] & 0xFFFF);
                Vt[(sdq + 2 * i + 1) * 136 + nl] = (u16)(vwv[i] >> 16);
            }
        }
        __syncthreads();
        #pragma unroll
        for (int k0 = 0; k0 < 128; k0 += 32) {
            f16x8 af[2], bv[2];
            #pragma unroll
            for (int i = 0; i < 2; ++i) {
                af[i] = *(const f16x8*)&Kt[(dh + i * 16 + l15) * 136 + k0 + kb8];
                bv[i] = *(const f16x8*)&Vt[(eh + i * 16 + l15) * 136 + k0 + kb8];
            }
            #pragma unroll
            for (int i = 0; i < 2; ++i)
                #pragma unroll
                for (int j = 0; j < 2; ++j)
                    accA[i][j] = __builtin_amdgcn_mfma_f32_16x16x32_f16(af[i], bv[j], accA[i][j], 0, 0, 0);
        }
    }
    __syncthreads();   // all waves done with Kt/Vt before overwrite

    // ---- write kv^T (fp16, exact: integers <= 196) and stage Q
    #pragma unroll
    for (int i = 0; i < 2; ++i)
        #pragma unroll
        for (int j = 0; j < 2; ++j)
            #pragma unroll
            for (int r = 0; r < 4; ++r) {
                int e = eh + j * 16 + l15;
                int d = dh + i * 16 + quad + r;
                _Float16 hv = (_Float16)accA[i][j][r];
                kvT[e * 72 + d] = h_bits(hv);
            }
    #pragma unroll
    for (int p = 0; p < 4; ++p) {
        int n = p * 64 + srow;
        if (n < 208) {
            if (n < NN) {
                const u16* qr = Q + gb + (size_t)n * CC + sdq;
                uint4 qa  = *(const uint4*)qr;
                uint4 qb2 = *(const uint4*)(qr + 8);
                u32 qwv[8] = {qa.x, qa.y, qa.z, qa.w, qb2.x, qb2.y, qb2.z, qb2.w};
                #pragma unroll
                for (int i = 0; i < 8; ++i) {
                    Qs[n * 72 + sdq + 2 * i]     = (u16)(qwv[i] & 0xFFFF);
                    Qs[n * 72 + sdq + 2 * i + 1] = (u16)(qwv[i] >> 16);
                }
            } else {
                #pragma unroll
                for (int i = 0; i < 16; ++i) Qs[n * 72 + sdq + i] = 0;
            }
        }
    }
    __syncthreads();

    // ---- phase B: wave w owns e-tile [w*16, w*16+16)
    f16x8 bq0 = *(const f16x8*)&kvT[(w * 16 + l15) * 72 + 0  + kb8];
    f16x8 bq1 = *(const f16x8*)&kvT[(w * 16 + l15) * 72 + 32 + kb8];
    u16* ob = OS + (size_t)tb * NN * CC + (size_t)h * HD + w * 16 + l15;
    #pragma unroll
    for (int nt = 0; nt < 13; ++nt) {
        f32x4 acc = zz;
        f16x8 a0 = *(const f16x8*)&Qs[(nt * 16 + l15) * 72 + 0  + kb8];
        f16x8 a1 = *(const f16x8*)&Qs[(nt * 16 + l15) * 72 + 32 + kb8];
        acc = __builtin_amdgcn_mfma_f32_16x16x32_f16(a0, bq0, acc, 0, 0, 0);
        acc = __builtin_amdgcn_mfma_f32_16x16x32_f16(a1, bq1, acc, 0, 0, 0);
        #pragma unroll
        for (int r = 0; r < 4; ++r) {
            int n = nt * 16 + quad + r;
            if (n < NN) {
                _Float16 ov = (_Float16)(acc[r] * 0.125f);
                ob[(size_t)n * CC] = h_bits(ov);
            }
        }
    }
}

// ---------------- attn LIF (vth=0.5), compact flat, in place on fp16 ----------------
__global__ __launch_bounds__(256) void k_attn_lif(u16* __restrict__ OS) {
    size_t idx = (size_t)blockIdx.x * 256 + threadIdx.x;   // flat over one t-slice
    float v = 0.f;
    #pragma unroll
    for (int t = 0; t < TT; ++t) {
        size_t off = idx + (size_t)t * CSTRIDE;
        float xv = h2f(OS[off]);
        float h = v + (xv - v) * 0.5f;
        bool s = (h >= 0.5f);
        v = s ? 0.f : h;
        OS[off] = s ? ONE_H : 0;
    }
}

// ---------------- final projection GEMM: out[tb][o][n], compact rows, 2-plane fp16, BK=64 ----------------
__global__ __launch_bounds__(256) void k_gemm_proj(const u16* __restrict__ S, const u16* __restrict__ W2,
                                                   const float* __restrict__ scale, const float* __restrict__ shift,
                                                   float* __restrict__ Y) {
    __shared__ __align__(16) u16 Xt[128 * 64];
    __shared__ __align__(16) u16 Wt[2][128 * 64];
    const int tid  = threadIdx.x;
    const int lane = tid & 63;
    const int w    = tid >> 6;
    const int bid  = blockIdx.x;
    const int work = (bid & 7) * 98 + (bid >> 3);
    const int ntile = work >> 2;    // 0..195
    const int wtile = work & 3;     // 0..3
    const u16* Sb = S + (size_t)ntile * 128 * CC;
    const u16* Wb = W2 + (size_t)(wtile * 128) * CC;

    const int lrow8  = lane >> 3;
    const int gchunk = ((lane & 7) ^ lrow8) * 8;
    const int l15 = lane & 15;
    const int q4  = lane >> 4;
    const int wm = (w >> 1) * 64, wn = (w & 1) * 64;

    // a 128-row tile crosses at most one tb boundary
    const int tb0 = (ntile * 128) / NN;
    const int bnd = (tb0 + 1) * NN;

    f32x4 acc[4][4];
    f32x4 zz = {0.f, 0.f, 0.f, 0.f};
    #pragma unroll
    for (int i = 0; i < 4; ++i)
        #pragma unroll
        for (int j = 0; j < 4; ++j) acc[i][j] = zz;

    for (int c0 = 0; c0 < CC; c0 += 64) {
        __syncthreads();
        #pragma unroll
        for (int i = 0; i < 4; ++i) {
            int p = w * 4 + i;
            gld16(Sb + (size_t)(p * 8 + lrow8) * CC + c0 + gchunk, &Xt[p * 512]);
        }
        #pragma unroll
        for (int i = 0; i < 8; ++i) {
            int lin = w * 8 + i;
            int s = lin >> 4, p = lin & 15;
            gld16(Wb + (size_t)s * 262144 + (size_t)(p * 8 + lrow8) * CC + c0 + gchunk,
                  &Wt[s][p * 512]);
        }
        __syncthreads();

        #pragma unroll
        for (int ks = 0; ks < 2; ++ks) {
            const int cpo = ((ks * 4 + q4) ^ (l15 & 7)) * 8;
            f16x8 sf[4], sflo[4];
            #pragma unroll
            for (int i = 0; i < 4; ++i) {
                sf[i]   = *(const f16x8*)&Xt[(wn + i * 16 + l15) * 64 + cpo];
                sflo[i] = sf[i] * (_Float16)0.00048828125f;   // 2^-11
            }
            #pragma unroll
            for (int s = 0; s < 2; ++s) {
                f16x8 wf[4];
                #pragma unroll
                for (int i = 0; i < 4; ++i)
                    wf[i] = *(const f16x8*)&Wt[s][(wm + i * 16 + l15) * 64 + cpo];
                #pragma unroll
                for (int mt = 0; mt < 4; ++mt)
                    #pragma unroll
                    for (int nt = 0; nt < 4; ++nt)
                        acc[mt][nt] = __builtin_amdgcn_mfma_f32_16x16x32_f16(
                            wf[mt], s ? sflo[nt] : sf[nt], acc[mt][nt], 0, 0, 0);
            }
        }
    }

    #pragma unroll
    for (int mt = 0; mt < 4; ++mt) {
        int o0 = wtile * 128 + wm + mt * 16 + (lane >> 4) * 4;
        #pragma unroll
        for (int nt = 0; nt < 4; ++nt) {
            int row = ntile * 128 + wn + nt * 16 + l15;
            int tb = (row >= bnd) ? tb0 + 1 : tb0;
            int n  = row - tb * NN;
            #pragma unroll
            for (int r = 0; r < 4; ++r)
                Y[((size_t)tb * CC + o0 + r) * NN + n] = acc[mt][nt][r] * scale[o0 + r] + shift[o0 + r];
        }
    }
}

extern "C" void kernel_launch(void* const* d_in, const int* in_sizes, int n_in,
                              void* d_out, int out_size, void* d_ws, size_t ws_size,
                              hipStream_t stream) {
    const float* x    = (const float*)d_in[0];
    const float* q_cw = (const float*)d_in[1];
    const float* q_cb = (const float*)d_in[2];
    const float* q_bg = (const float*)d_in[3];
    const float* q_bb = (const float*)d_in[4];
    const float* q_bm = (const float*)d_in[5];
    const float* q_bv = (const float*)d_in[6];
    const float* k_cw = (const float*)d_in[7];
    const float* k_cb = (const float*)d_in[8];
    const float* k_bg = (const float*)d_in[9];
    const float* k_bb = (const float*)d_in[10];
    const float* k_bm = (const float*)d_in[11];
    const float* k_bv = (const float*)d_in[12];
    const float* v_cw = (const float*)d_in[13];
    const float* v_cb = (const float*)d_in[14];
    const float* v_bg = (const float*)d_in[15];
    const float* v_bb = (const float*)d_in[16];
    const float* v_bm = (const float*)d_in[17];
    const float* v_bv = (const float*)d_in[18];
    const float* p_cw = (const float*)d_in[19];
    const float* p_cb = (const float*)d_in[20];
    const float* p_bg = (const float*)d_in[21];
    const float* p_bb = (const float*)d_in[22];
    const float* p_bm = (const float*)d_in[23];
    const float* p_bv = (const float*)d_in[24];
    const float* pshw = (const float*)d_in[25];
    const float* pllw = (const float*)d_in[26];
    const float* ppb  = (const float*)d_in[27];
    float* out = (float*)d_out;

    // ws map (compact layouts, 242 MB budget):
    //   [0,26)    XS head spikes (25.7MB); reused as QS after gemm_qkv
    //   [26,78)   Yq fp32 (51.4MB); [26,52) reused as OS after attn inputs consumed
    //   [78,130)  Yk fp32
    //   [130,182) Yv fp32
    //   [182,208) KS ; [208,234) VS
    //   [234,238) W2 (4MB) ; then SS/SH
    if (ws_size < (size_t)242 * 1024 * 1024) return;
    char* W = (char*)d_ws;
    u16*   XS = (u16*)W;
    u16*   QS = (u16*)W;
    float* Yq = (float*)(W + ((size_t)26 << 20));
    float* Yk = (float*)(W + ((size_t)78 << 20));
    float* Yv = (float*)(W + ((size_t)130 << 20));
    u16*   KS = (u16*)(W + ((size_t)182 << 20));
    u16*   VS = (u16*)(W + ((size_t)208 << 20));
    u16*   OS = (u16*)(W + ((size_t)26 << 20));   // overwrites Yq (dead after k_lif_all)
    u16*   W2 = (u16*)(W + ((size_t)234 << 20));
    float* SS = (float*)(W + ((size_t)238 << 20));            // scale[4][512]
    float* SH = SS + 2048;                                     // shift[4][512]

    k_prep<<<4104, 256, 0, stream>>>(q_cw, k_cw, v_cw, p_cw,
                                     q_cb, q_bg, q_bb, q_bm, q_bv,
                                     k_cb, k_bg, k_bb, k_bm, k_bv,
                                     v_cb, v_bg, v_bb, v_bm, v_bv,
                                     p_cb, p_bg, p_bb, p_bm, p_bv, W2, SS, SH);

    k_head_lif<<<dim3(4, 32, 8), 256, 0, stream>>>(x, XS);

    // merged Q/K/V projection, XCD-swizzled 1D grid; Yq,Yk,Yv at 52MB stride
    k_gemm_qkv<<<2352, 256, 0, stream>>>(XS, W2, SS, SH, Yq);

    // all 5 LIF chains in one launch -> compact fp16 spikes
    const int validBlocks = (int)(CSTRIDE / 256);   // 12544
    k_lif_all<<<validBlocks, 256, 0, stream>>>(Yq, Yk, Yv, QS, KS, VS, pshw, pllw, ppb);

    k_attn<<<TBB * NHH, 256, 0, stream>>>(QS, KS, VS, OS);
    k_attn_lif<<<validBlocks, 256, 0, stream>>>(OS);

    k_gemm_proj<<<784, 256, 0, stream>>>(OS, W2 + 3 * 524288, SS + 1536, SH + 1536, out);
}